// Round 7
// baseline (228.552 us; speedup 1.0000x reference)
//
#include <hip/hip_runtime.h>
#include <hip/hip_bf16.h>

#define DEVFN __device__ __forceinline__

typedef __bf16 bf16x8 __attribute__((ext_vector_type(8)));
typedef float f32x4 __attribute__((ext_vector_type(4)));
typedef float float4_t __attribute__((ext_vector_type(4)));
typedef unsigned short ushort8_t __attribute__((ext_vector_type(8)));
typedef unsigned short ushort4_t __attribute__((ext_vector_type(4)));
typedef unsigned int uint4_t __attribute__((ext_vector_type(4)));

constexpr int Bd = 8, Cd = 512, Nd = 4096, Dd = 64;

DEVFN unsigned short f2bf(float f) {
    union { float f; unsigned int u; } v; v.f = f;
    unsigned int r = (v.u + 0x7FFFu + ((v.u >> 16) & 1u)) >> 16;
    return (unsigned short)r;
}

DEVFN unsigned int pack2(float a, float b) {   // two f32 -> packed bf16x2 (RNE)
    __hip_bfloat162 h = __float22bfloat162_rn(make_float2(a, b));
    union { __hip_bfloat162 h; unsigned int u; } c; c.h = h;
    return c.u;
}

DEVFN bf16x8 ld_bf8(const unsigned short* p) {
    ushort8_t u = *(const ushort8_t*)p;
    return __builtin_bit_cast(bf16x8, u);
}

DEVFN f32x4 mfma16(bf16x8 a, bf16x8 b, f32x4 c) {
    return __builtin_amdgcn_mfma_f32_16x16x32_bf16(a, b, c, 0, 0, 0);
}

// ---------------- K0: convert weights to bf16 ----------------
__global__ __launch_bounds__(256) void k_cvtw(
    const float* __restrict__ Wq, const float* __restrict__ Wk,
    const float* __restrict__ Wv, const float* __restrict__ Wo,
    unsigned short* __restrict__ w4)
{
    int i = blockIdx.x * 256 + threadIdx.x;   // 0..32767
    w4[i]          = f2bf(Wq[i]);
    w4[32768 + i]  = f2bf(Wk[i]);
    w4[65536 + i]  = f2bf(Wv[i]);
    w4[98304 + i]  = f2bf(Wo[i]);
}

// ---------------- K1 v2: fused x-transpose + QKV GEMM ----------------
// out(N,D) = x^T W^T per batch. Block: 32 n-rows, full C=512 contraction.
// x tile (64c x 32n f32) -> LDS transposed bf16 [32n][64c(+8 pad)]; A-fragments
// are single ds_read_b128; B-fragments are contiguous 16B weight loads (L2-hot).
// 4 waves = 2 n-subtiles x 2 output-halves (each wave 6 of 12 q/k/v d-tiles).
__global__ __launch_bounds__(256, 4) void k_qkv(
    const float* __restrict__ x,
    const unsigned short* __restrict__ wq,
    const unsigned short* __restrict__ wk,
    const unsigned short* __restrict__ wv,
    const float* __restrict__ bq, const float* __restrict__ bk, const float* __restrict__ bv,
    unsigned short* __restrict__ q_nd, unsigned short* __restrict__ k_nd,
    unsigned short* __restrict__ v_dn)
{
    const int b   = blockIdx.y;
    const int n0  = blockIdx.x * 32;
    const int tid = threadIdx.x, wid = tid >> 6, l = tid & 63;
    const int lo  = l & 15, hi = l >> 4;
    const int ns  = wid >> 1;            // n-subtile (16 rows)
    const int oh  = wid & 1;             // output-half (6 of 12 d-tiles)
    const float* xb = x + (size_t)b * Cd * Nd;

    __shared__ unsigned short xt[2][32][72];   // [buf][n-local][c-local + pad]

    f32x4 acc[6] = {};

    // staging: thread -> c-row scr (0..31; also scr+32), n-chunk snf*4
    const int scr = tid >> 3, snf = tid & 7;
    float4_t xr0, xr1;

    auto gload = [&](int t) {
        const int c0 = t * 64;
        xr0 = *(const float4_t*)(xb + (size_t)(c0 + scr)      * Nd + n0 + snf * 4);
        xr1 = *(const float4_t*)(xb + (size_t)(c0 + 32 + scr) * Nd + n0 + snf * 4);
    };
    auto dswrite = [&](int buf) {
        #pragma unroll
        for (int i = 0; i < 4; ++i) {
            xt[buf][snf * 4 + i][scr]      = f2bf(xr0[i]);
            xt[buf][snf * 4 + i][32 + scr] = f2bf(xr1[i]);
        }
    };
    auto compute = [&](int buf, int t) {
        #pragma unroll
        for (int kk = 0; kk < 2; ++kk) {
            const int c0 = t * 64 + kk * 32;
            bf16x8 af = ld_bf8(&xt[buf][ns * 16 + lo][kk * 32 + hi * 8]);
            #pragma unroll
            for (int j = 0; j < 6; ++j) {
                const int dt  = oh + 2 * j;
                const unsigned short* wmat = (dt < 4) ? wq : (dt < 8) ? wk : wv;
                const int d0  = (dt & 3) * 16;
                bf16x8 bf = ld_bf8(wmat + (d0 + lo) * Cd + c0 + hi * 8);
                acc[j] = mfma16(af, bf, acc[j]);
            }
        }
    };

    gload(0);
    dswrite(0);
    __syncthreads();
    for (int t = 0; t < 8; ++t) {
        const int cur = t & 1;
        if (t + 1 < 8) gload(t + 1);             // issue early: hidden under compute
        __builtin_amdgcn_sched_barrier(0);       // pin loads (round-2 sinking lesson)
        compute(cur, t);
        if (t + 1 < 8) dswrite(cur ^ 1);         // other buffer: no reader this tile
        __syncthreads();                         // one barrier per chunk
    }

    // epilogue: bias + store. D-tile: row = n-local (hi*4+r), col = d (lo).
    #pragma unroll
    for (int j = 0; j < 6; ++j) {
        const int dt  = oh + 2 * j;
        const int mat = dt >> 2, d0 = (dt & 3) * 16;
        const float bia = (mat == 0 ? bq : mat == 1 ? bk : bv)[d0 + lo];
        if (mat < 2) {
            unsigned short* dst = (mat == 0 ? q_nd : k_nd)
                + ((size_t)b * Nd + n0 + ns * 16 + hi * 4) * 64 + d0 + lo;
            #pragma unroll
            for (int r = 0; r < 4; ++r)
                dst[(size_t)r * 64] = f2bf(acc[j][r] + bia);
        } else {
            ushort4_t u;
            #pragma unroll
            for (int r = 0; r < 4; ++r) u[r] = f2bf(acc[j][r] + bia);
            *(ushort4_t*)(v_dn + ((size_t)b * Dd + d0 + lo) * Nd + n0 + ns * 16 + hi * 4) = u;
        }
    }
}

// ---------------- K2: flash attention, 2qh x 2kh wave split, lane-local P ----------------
// (unchanged from round 6 — validated)
__global__ __launch_bounds__(256, 2) void k_attn(
    const unsigned short* __restrict__ q_nd,
    const unsigned short* __restrict__ k_nd,
    const unsigned short* __restrict__ v_dn,
    unsigned short* __restrict__ o_nd)
{
    const int bid = blockIdx.x;
    const int b   = bid & 7;            // round-robin XCD dispatch -> batch-per-XCD L2 locality
    const int n0  = (bid >> 3) * 64;
    const int tid = threadIdx.x, wid = tid >> 6, l = tid & 63;
    const int lo  = l & 15, hi = l >> 4;
    const int lsw = lo & 7;
    const int qh  = wid >> 1;           // q-half (32 rows)
    const int kh  = wid & 1;            // key-half (32 keys)
    const int wk0 = kh * 32;

    __shared__ unsigned short k_tiles[2][64 * 64];
    __shared__ unsigned short v_tiles[2][64 * 64];
    __shared__ float red_acc[2][2][4][256];   // [qh][qs][ds][lane*4]
    __shared__ float red_l[2][2][16];         // [qh][qs][lo]

    const unsigned short* qb = q_nd + (size_t)b * Nd * Dd;
    const unsigned short* kb = k_nd + (size_t)b * Nd * Dd;
    const unsigned short* vb = v_dn + (size_t)b * Dd * Nd;

    bf16x8 aq[2][2];
    #pragma unroll
    for (int qs = 0; qs < 2; ++qs)
        #pragma unroll
        for (int kc = 0; kc < 2; ++kc)
            aq[qs][kc] = ld_bf8(qb + (size_t)(n0 + qh*32 + qs*16 + lo) * 64 + kc*32 + hi*8);

    f32x4 acc[2][4] = {};
    float l_p[2] = {0.f, 0.f};

    const int sr = tid >> 3, ss = tid & 7;
    const int kwsl = (ss ^ (sr & 7)) * 8;
    const int vkh = ss >> 2, vsl = ss & 3, vms = vsl >> 1;
    const int vg0 = vkh * 4 + ((2 * vsl) & 3);
    const int vg1 = vkh * 4 + ((2 * vsl + 1) & 3);
    const int vsw = sr & 7;
    ushort8_t kr0, kr1, vr0, vr1;

    auto gload = [&](int t) {
        const size_t m1 = (size_t)t * 64;
        kr0 = *(const ushort8_t*)(kb + (m1 + sr) * 64 + ss * 8);
        kr1 = *(const ushort8_t*)(kb + (m1 + 32 + sr) * 64 + ss * 8);
        vr0 = *(const ushort8_t*)(vb + (size_t)sr * Nd + m1 + ss * 8);
        vr1 = *(const ushort8_t*)(vb + (size_t)(32 + sr) * Nd + m1 + ss * 8);
    };
    auto dswrite = [&](int buf) {
        unsigned short* kt = k_tiles[buf];
        unsigned short* vt = v_tiles[buf];
        *(ushort8_t*)(kt + sr * 64 + kwsl)        = kr0;
        *(ushort8_t*)(kt + (32 + sr) * 64 + kwsl) = kr1;
        ushort4_t a0 = __builtin_shufflevector(vr0, vr0, 0, 1, 2, 3);
        ushort4_t a1 = __builtin_shufflevector(vr0, vr0, 4, 5, 6, 7);
        ushort4_t b0 = __builtin_shufflevector(vr1, vr1, 0, 1, 2, 3);
        ushort4_t b1 = __builtin_shufflevector(vr1, vr1, 4, 5, 6, 7);
        *(ushort4_t*)(vt + sr * 64 + (vg0 ^ vsw) * 8 + vms * 4)        = a0;
        *(ushort4_t*)(vt + sr * 64 + (vg1 ^ vsw) * 8 + vms * 4)        = a1;
        *(ushort4_t*)(vt + (32 + sr) * 64 + (vg0 ^ vsw) * 8 + vms * 4) = b0;
        *(ushort4_t*)(vt + (32 + sr) * 64 + (vg1 ^ vsw) * 8 + vms * 4) = b1;
    };

    auto compute = [&](int buf) {
        const unsigned short* kt = k_tiles[buf];
        const unsigned short* vt = v_tiles[buf];
        f32x4 s[2][2] = {};
        #pragma unroll
        for (int ms = 0; ms < 2; ++ms) {
            #pragma unroll
            for (int kc = 0; kc < 2; ++kc) {
                bf16x8 kf = ld_bf8(kt + (wk0 + ms*16 + lo) * 64 + (((kc*4 + hi) ^ lsw) * 8));
                #pragma unroll
                for (int qs = 0; qs < 2; ++qs)
                    s[qs][ms] = mfma16(kf, aq[qs][kc], s[qs][ms]);
            }
        }
        bf16x8 vf[4];
        #pragma unroll
        for (int ds = 0; ds < 4; ++ds)
            vf[ds] = ld_bf8(vt + (ds*16 + lo) * 64 + (((kh*4 + hi) ^ lsw) * 8));
        #pragma unroll
        for (int qs = 0; qs < 2; ++qs) {
            float p[2][4];
            #pragma unroll
            for (int ms = 0; ms < 2; ++ms)
                #pragma unroll
                for (int r = 0; r < 4; ++r)
                    p[ms][r] = __expf(s[qs][ms][r]);
            l_p[qs] += ((p[0][0] + p[0][1]) + (p[0][2] + p[0][3]))
                     + ((p[1][0] + p[1][1]) + (p[1][2] + p[1][3]));
            uint4_t w;
            w[0] = pack2(p[0][0], p[0][1]);
            w[1] = pack2(p[0][2], p[0][3]);
            w[2] = pack2(p[1][0], p[1][1]);
            w[3] = pack2(p[1][2], p[1][3]);
            bf16x8 apf = __builtin_bit_cast(bf16x8, w);
            #pragma unroll
            for (int ds = 0; ds < 4; ++ds)
                acc[qs][ds] = mfma16(apf, vf[ds], acc[qs][ds]);
        }
    };

    constexpr int NT = Nd / 64;
    gload(0);
    dswrite(0);
    __syncthreads();
    for (int t = 0; t < NT; ++t) {
        const int cur = t & 1;
        if (t + 1 < NT) gload(t + 1);
        __builtin_amdgcn_sched_barrier(0);
        compute(cur);
        if (t + 1 < NT) dswrite(cur ^ 1);
        __syncthreads();
    }

    float lh[2];
    #pragma unroll
    for (int qs = 0; qs < 2; ++qs) {
        float ps = l_p[qs];
        ps += __shfl_xor(ps, 16, 64);
        ps += __shfl_xor(ps, 32, 64);
        lh[qs] = ps;
    }
    if (kh == 1) {
        #pragma unroll
        for (int qs = 0; qs < 2; ++qs) {
            #pragma unroll
            for (int ds = 0; ds < 4; ++ds)
                *(f32x4*)&red_acc[qh][qs][ds][l * 4] = acc[qs][ds];
            red_l[qh][qs][lo] = lh[qs];
        }
    }
    __syncthreads();
    if (kh == 0) {
        #pragma unroll
        for (int qs = 0; qs < 2; ++qs) {
            #pragma unroll
            for (int ds = 0; ds < 4; ++ds)
                acc[qs][ds] += *(const f32x4*)&red_acc[qh][qs][ds][l * 4];
            float l_tot = lh[qs] + red_l[qh][qs][lo];
            #pragma unroll
            for (int r = 0; r < 4; ++r) {
                float lq = __shfl(l_tot, hi * 4 + r, 16);
                float rl = 1.0f / lq;
                #pragma unroll
                for (int ds = 0; ds < 4; ++ds) {
                    float o = acc[qs][ds][r] * rl;
                    o_nd[((size_t)b * Nd + n0 + qh*32 + qs*16 + hi*4 + r) * 64 + ds*16 + lo] = f2bf(o);
                }
            }
        }
    }
}

// ---------------- K3: output projection + residual ----------------
__global__ __launch_bounds__(256) void k_oproj(
    const unsigned short* __restrict__ o_nd,
    const unsigned short* __restrict__ wo,
    const float* __restrict__ bo,
    const float* __restrict__ gamma,
    const float* __restrict__ x,
    float* __restrict__ out)
{
    const int b   = blockIdx.y;
    const int n0  = blockIdx.x * 64;
    const int tid = threadIdx.x, wid = tid >> 6, l = tid & 63;
    const int lo  = l & 15, hi = l >> 4;
    const int n0w = n0 + wid * 16;
    const float g = gamma[0];

    bf16x8 ao[2];
    #pragma unroll
    for (int kc = 0; kc < 2; ++kc)
        ao[kc] = ld_bf8(o_nd + ((size_t)b * Nd + n0w + lo) * 64 + kc*32 + hi*8);

    for (int ct = 0; ct < 32; ++ct) {
        f32x4 acc = {};
        #pragma unroll
        for (int kc = 0; kc < 2; ++kc) {
            bf16x8 bw = ld_bf8(wo + (ct*16 + lo) * 64 + kc*32 + hi*8);
            acc = mfma16(ao[kc], bw, acc);
        }
        const int c = ct*16 + lo;
        const float bc = bo[c];
        const size_t base = ((size_t)b * Cd + c) * Nd + n0w + hi*4;
        float4_t xv = *(const float4_t*)(x + base);
        float4_t ov;
        #pragma unroll
        for (int r = 0; r < 4; ++r) ov[r] = g * (acc[r] + bc) + xv[r];
        *(float4_t*)(out + base) = ov;
    }
}

extern "C" void kernel_launch(void* const* d_in, const int* in_sizes, int n_in,
                              void* d_out, int out_size, void* d_ws, size_t ws_size,
                              hipStream_t stream) {
    (void)in_sizes; (void)n_in; (void)out_size; (void)ws_size;
    const float* x  = (const float*)d_in[0];
    const float* Wq = (const float*)d_in[1];
    const float* bq = (const float*)d_in[2];
    const float* Wk = (const float*)d_in[3];
    const float* bk = (const float*)d_in[4];
    const float* Wv = (const float*)d_in[5];
    const float* bv = (const float*)d_in[6];
    const float* Wo = (const float*)d_in[7];
    const float* bo = (const float*)d_in[8];
    const float* gm = (const float*)d_in[9];
    float* out = (float*)d_out;

    unsigned short* w4   = (unsigned short*)d_ws;          // 4 x 32768 bf16 weights
    unsigned short* q_nd = w4 + 131072;
    unsigned short* k_nd = q_nd + (size_t)Bd * Nd * Dd;
    unsigned short* v_dn = k_nd + (size_t)Bd * Nd * Dd;
    unsigned short* o_nd = v_dn + (size_t)Bd * Nd * Dd;

    k_cvtw<<<128, 256, 0, stream>>>(Wq, Wk, Wv, Wo, w4);
    dim3 gq(Nd / 32, Bd);
    k_qkv<<<gq, 256, 0, stream>>>(x, w4, w4 + 32768, w4 + 65536, bq, bk, bv, q_nd, k_nd, v_dn);
    k_attn<<<512, 256, 0, stream>>>(q_nd, k_nd, v_dn, o_nd);
    dim3 g1(Nd / 64, Bd);
    k_oproj<<<g1, 256, 0, stream>>>(o_nd, w4 + 98304, bo, gm, x, out);
}

// Round 8
// 152.246 us; speedup vs baseline: 1.5012x; 1.5012x over previous
//
#include <hip/hip_runtime.h>
#include <hip/hip_bf16.h>

#define DEVFN __device__ __forceinline__

typedef __bf16 bf16x8 __attribute__((ext_vector_type(8)));
typedef float f32x4 __attribute__((ext_vector_type(4)));
typedef float float4_t __attribute__((ext_vector_type(4)));
typedef unsigned short ushort8_t __attribute__((ext_vector_type(8)));
typedef unsigned short ushort4_t __attribute__((ext_vector_type(4)));
typedef unsigned int uint4_t __attribute__((ext_vector_type(4)));

constexpr int Bd = 8, Cd = 512, Nd = 4096, Dd = 64;

DEVFN unsigned short f2bf(float f) {
    union { float f; unsigned int u; } v; v.f = f;
    unsigned int r = (v.u + 0x7FFFu + ((v.u >> 16) & 1u)) >> 16;
    return (unsigned short)r;
}

DEVFN unsigned int pack2(float a, float b) {   // two f32 -> packed bf16x2 (RNE)
    __hip_bfloat162 h = __float22bfloat162_rn(make_float2(a, b));
    union { __hip_bfloat162 h; unsigned int u; } c; c.h = h;
    return c.u;
}

DEVFN bf16x8 ld_bf8(const unsigned short* p) {
    ushort8_t u = *(const ushort8_t*)p;
    return __builtin_bit_cast(bf16x8, u);
}

DEVFN f32x4 mfma16(bf16x8 a, bf16x8 b, f32x4 c) {
    return __builtin_amdgcn_mfma_f32_16x16x32_bf16(a, b, c, 0, 0, 0);
}

// ---------------- K0: convert weights to bf16 ----------------
__global__ __launch_bounds__(256) void k_cvtw(
    const float* __restrict__ Wq, const float* __restrict__ Wk,
    const float* __restrict__ Wv, const float* __restrict__ Wo,
    unsigned short* __restrict__ w4)
{
    int i = blockIdx.x * 256 + threadIdx.x;   // 0..32767
    w4[i]          = f2bf(Wq[i]);
    w4[32768 + i]  = f2bf(Wk[i]);
    w4[65536 + i]  = f2bf(Wv[i]);
    w4[98304 + i]  = f2bf(Wo[i]);
}

// ---------------- K1 v3: QKV = coalesced-load LDS transpose + GEMM + coalesced-store epilogue ----
// out(N,D) = x^T W^T per batch. Block: 64 n-rows, full C=512 contraction, 4 waves
// (wave = 16 n-rows x all 12 d-tiles of q,k,v).
// Input:  x chunk [64c][64n] f32 read as float4 (256B rows), written transposed+
//         converted into LDS xt[64n][64c+8]; A-fragment = one ds_read_b128.
// Weights: B-fragments contiguous 16B from global (L2-hot, 192 KB).
// Output: q/k via per-wave LDS transpose -> 2KB-contiguous ushort8 stores;
//         v via block-wide transpose -> 128B segments (round-6 proven epilogue).
__global__ __launch_bounds__(256, 1) void k_qkv(
    const float* __restrict__ x,
    const unsigned short* __restrict__ wq,
    const unsigned short* __restrict__ wk,
    const unsigned short* __restrict__ wv,
    const float* __restrict__ bq, const float* __restrict__ bk, const float* __restrict__ bv,
    unsigned short* __restrict__ q_nd, unsigned short* __restrict__ k_nd,
    unsigned short* __restrict__ v_dn)
{
    const int b   = blockIdx.y;
    const int n0  = blockIdx.x * 64;
    const int tid = threadIdx.x, wid = tid >> 6, l = tid & 63;
    const int lo  = l & 15, hi = l >> 4;
    const float* xb = x + (size_t)b * Cd * Nd;

    __shared__ unsigned short smem[2][64][72];   // xt double-buffer; reused by epilogue

    f32x4 acc[12] = {};

    // staging: thread -> c-rows (p*16 + scr), n-chunk snf*4 (float4)
    const int scr = tid >> 4;      // 0..15
    const int snf = tid & 15;      // 0..15
    float4_t xr[4];

    auto gload = [&](int t) {
        const int c0 = t * 64;
        #pragma unroll
        for (int p = 0; p < 4; ++p)
            xr[p] = *(const float4_t*)(xb + (size_t)(c0 + p*16 + scr) * Nd + n0 + snf*4);
    };
    auto dswrite = [&](int buf) {
        #pragma unroll
        for (int p = 0; p < 4; ++p)
            #pragma unroll
            for (int i = 0; i < 4; ++i)
                smem[buf][snf*4 + i][p*16 + scr] = f2bf(xr[p][i]);
    };
    auto compute = [&](int buf, int t) {
        const int c0 = t * 64;
        #pragma unroll
        for (int kk = 0; kk < 2; ++kk) {
            bf16x8 af = ld_bf8(&smem[buf][wid*16 + lo][kk*32 + hi*8]);
            #pragma unroll
            for (int j = 0; j < 12; ++j) {
                const unsigned short* wm = (j < 4) ? wq : (j < 8) ? wk : wv;
                const int d0 = (j & 3) * 16;
                bf16x8 bf = ld_bf8(wm + (d0 + lo) * Cd + c0 + kk*32 + hi*8);
                acc[j] = mfma16(af, bf, acc[j]);
            }
        }
    };

    gload(0);
    dswrite(0);
    __syncthreads();
    for (int t = 0; t < 8; ++t) {
        const int cur = t & 1;
        if (t + 1 < 8) gload(t + 1);             // issue early: hidden under compute
        __builtin_amdgcn_sched_barrier(0);       // pin loads (round-2 sinking lesson)
        compute(cur, t);
        if (t + 1 < 8) dswrite(cur ^ 1);         // other buffer: no reader this tile
        __syncthreads();
    }

    // ---- epilogue: q/k via per-wave transpose (smem[0], wave-private rows) ----
    unsigned short* tl = &smem[0][wid*16][0];    // [16 n-local][72]
    #pragma unroll
    for (int m = 0; m < 2; ++m) {
        const float* bias = m ? bk : bq;
        #pragma unroll
        for (int jj = 0; jj < 4; ++jj) {
            const float bia = bias[jj*16 + lo];
            #pragma unroll
            for (int r = 0; r < 4; ++r)
                tl[(hi*4 + r) * 72 + jj*16 + lo] = f2bf(acc[m*4 + jj][r] + bia);
        }
        asm volatile("" ::: "memory");           // in-wave: reads after writes
        const int row = l >> 2, dg = l & 3;
        ushort8_t a0 = *(const ushort8_t*)&tl[row*72 + dg*16];
        ushort8_t a1 = *(const ushort8_t*)&tl[row*72 + dg*16 + 8];
        unsigned short* dst = (m ? k_nd : q_nd)
            + ((size_t)b * Nd + n0 + wid*16 + row) * 64 + dg*16;
        *(ushort8_t*)dst = a0; *(ushort8_t*)(dst + 8) = a1;
        asm volatile("" ::: "memory");           // m=0 reads before m=1 overwrites
    }

    // ---- epilogue: v via block-wide transpose (smem[1]) ----
    #pragma unroll
    for (int jj = 0; jj < 4; ++jj) {
        const float bia = bv[jj*16 + lo];
        #pragma unroll
        for (int r = 0; r < 4; ++r)
            smem[1][jj*16 + lo][wid*16 + hi*4 + r] = f2bf(acc[8 + jj][r] + bia);
    }
    __syncthreads();
    {
        const int d = tid >> 2, ng = tid & 3;
        ushort8_t a0 = *(const ushort8_t*)&smem[1][d][ng*16];
        ushort8_t a1 = *(const ushort8_t*)&smem[1][d][ng*16 + 8];
        unsigned short* dst = v_dn + ((size_t)b * Dd + d) * Nd + n0 + ng*16;
        *(ushort8_t*)dst = a0; *(ushort8_t*)(dst + 8) = a1;
    }
}

// ---------------- K2: flash attention, 2qh x 2kh wave split, lane-local P ----------------
// (unchanged from round 6 — validated)
__global__ __launch_bounds__(256, 2) void k_attn(
    const unsigned short* __restrict__ q_nd,
    const unsigned short* __restrict__ k_nd,
    const unsigned short* __restrict__ v_dn,
    unsigned short* __restrict__ o_nd)
{
    const int bid = blockIdx.x;
    const int b   = bid & 7;            // round-robin XCD dispatch -> batch-per-XCD L2 locality
    const int n0  = (bid >> 3) * 64;
    const int tid = threadIdx.x, wid = tid >> 6, l = tid & 63;
    const int lo  = l & 15, hi = l >> 4;
    const int lsw = lo & 7;
    const int qh  = wid >> 1;           // q-half (32 rows)
    const int kh  = wid & 1;            // key-half (32 keys)
    const int wk0 = kh * 32;

    __shared__ unsigned short k_tiles[2][64 * 64];
    __shared__ unsigned short v_tiles[2][64 * 64];
    __shared__ float red_acc[2][2][4][256];   // [qh][qs][ds][lane*4]
    __shared__ float red_l[2][2][16];         // [qh][qs][lo]

    const unsigned short* qb = q_nd + (size_t)b * Nd * Dd;
    const unsigned short* kb = k_nd + (size_t)b * Nd * Dd;
    const unsigned short* vb = v_dn + (size_t)b * Dd * Nd;

    bf16x8 aq[2][2];
    #pragma unroll
    for (int qs = 0; qs < 2; ++qs)
        #pragma unroll
        for (int kc = 0; kc < 2; ++kc)
            aq[qs][kc] = ld_bf8(qb + (size_t)(n0 + qh*32 + qs*16 + lo) * 64 + kc*32 + hi*8);

    f32x4 acc[2][4] = {};
    float l_p[2] = {0.f, 0.f};

    const int sr = tid >> 3, ss = tid & 7;
    const int kwsl = (ss ^ (sr & 7)) * 8;
    const int vkh = ss >> 2, vsl = ss & 3, vms = vsl >> 1;
    const int vg0 = vkh * 4 + ((2 * vsl) & 3);
    const int vg1 = vkh * 4 + ((2 * vsl + 1) & 3);
    const int vsw = sr & 7;
    ushort8_t kr0, kr1, vr0, vr1;

    auto gload = [&](int t) {
        const size_t m1 = (size_t)t * 64;
        kr0 = *(const ushort8_t*)(kb + (m1 + sr) * 64 + ss * 8);
        kr1 = *(const ushort8_t*)(kb + (m1 + 32 + sr) * 64 + ss * 8);
        vr0 = *(const ushort8_t*)(vb + (size_t)sr * Nd + m1 + ss * 8);
        vr1 = *(const ushort8_t*)(vb + (size_t)(32 + sr) * Nd + m1 + ss * 8);
    };
    auto dswrite = [&](int buf) {
        unsigned short* kt = k_tiles[buf];
        unsigned short* vt = v_tiles[buf];
        *(ushort8_t*)(kt + sr * 64 + kwsl)        = kr0;
        *(ushort8_t*)(kt + (32 + sr) * 64 + kwsl) = kr1;
        ushort4_t a0 = __builtin_shufflevector(vr0, vr0, 0, 1, 2, 3);
        ushort4_t a1 = __builtin_shufflevector(vr0, vr0, 4, 5, 6, 7);
        ushort4_t b0 = __builtin_shufflevector(vr1, vr1, 0, 1, 2, 3);
        ushort4_t b1 = __builtin_shufflevector(vr1, vr1, 4, 5, 6, 7);
        *(ushort4_t*)(vt + sr * 64 + (vg0 ^ vsw) * 8 + vms * 4)        = a0;
        *(ushort4_t*)(vt + sr * 64 + (vg1 ^ vsw) * 8 + vms * 4)        = a1;
        *(ushort4_t*)(vt + (32 + sr) * 64 + (vg0 ^ vsw) * 8 + vms * 4) = b0;
        *(ushort4_t*)(vt + (32 + sr) * 64 + (vg1 ^ vsw) * 8 + vms * 4) = b1;
    };

    auto compute = [&](int buf) {
        const unsigned short* kt = k_tiles[buf];
        const unsigned short* vt = v_tiles[buf];
        f32x4 s[2][2] = {};
        #pragma unroll
        for (int ms = 0; ms < 2; ++ms) {
            #pragma unroll
            for (int kc = 0; kc < 2; ++kc) {
                bf16x8 kf = ld_bf8(kt + (wk0 + ms*16 + lo) * 64 + (((kc*4 + hi) ^ lsw) * 8));
                #pragma unroll
                for (int qs = 0; qs < 2; ++qs)
                    s[qs][ms] = mfma16(kf, aq[qs][kc], s[qs][ms]);
            }
        }
        bf16x8 vf[4];
        #pragma unroll
        for (int ds = 0; ds < 4; ++ds)
            vf[ds] = ld_bf8(vt + (ds*16 + lo) * 64 + (((kh*4 + hi) ^ lsw) * 8));
        #pragma unroll
        for (int qs = 0; qs < 2; ++qs) {
            float p[2][4];
            #pragma unroll
            for (int ms = 0; ms < 2; ++ms)
                #pragma unroll
                for (int r = 0; r < 4; ++r)
                    p[ms][r] = __expf(s[qs][ms][r]);
            l_p[qs] += ((p[0][0] + p[0][1]) + (p[0][2] + p[0][3]))
                     + ((p[1][0] + p[1][1]) + (p[1][2] + p[1][3]));
            uint4_t w;
            w[0] = pack2(p[0][0], p[0][1]);
            w[1] = pack2(p[0][2], p[0][3]);
            w[2] = pack2(p[1][0], p[1][1]);
            w[3] = pack2(p[1][2], p[1][3]);
            bf16x8 apf = __builtin_bit_cast(bf16x8, w);
            #pragma unroll
            for (int ds = 0; ds < 4; ++ds)
                acc[qs][ds] = mfma16(apf, vf[ds], acc[qs][ds]);
        }
    };

    constexpr int NT = Nd / 64;
    gload(0);
    dswrite(0);
    __syncthreads();
    for (int t = 0; t < NT; ++t) {
        const int cur = t & 1;
        if (t + 1 < NT) gload(t + 1);
        __builtin_amdgcn_sched_barrier(0);
        compute(cur);
        if (t + 1 < NT) dswrite(cur ^ 1);
        __syncthreads();
    }

    float lh[2];
    #pragma unroll
    for (int qs = 0; qs < 2; ++qs) {
        float ps = l_p[qs];
        ps += __shfl_xor(ps, 16, 64);
        ps += __shfl_xor(ps, 32, 64);
        lh[qs] = ps;
    }
    if (kh == 1) {
        #pragma unroll
        for (int qs = 0; qs < 2; ++qs) {
            #pragma unroll
            for (int ds = 0; ds < 4; ++ds)
                *(f32x4*)&red_acc[qh][qs][ds][l * 4] = acc[qs][ds];
            red_l[qh][qs][lo] = lh[qs];
        }
    }
    __syncthreads();
    if (kh == 0) {
        #pragma unroll
        for (int qs = 0; qs < 2; ++qs) {
            #pragma unroll
            for (int ds = 0; ds < 4; ++ds)
                acc[qs][ds] += *(const f32x4*)&red_acc[qh][qs][ds][l * 4];
            float l_tot = lh[qs] + red_l[qh][qs][lo];
            #pragma unroll
            for (int r = 0; r < 4; ++r) {
                float lq = __shfl(l_tot, hi * 4 + r, 16);
                float rl = 1.0f / lq;
                #pragma unroll
                for (int ds = 0; ds < 4; ++ds) {
                    float o = acc[qs][ds][r] * rl;
                    o_nd[((size_t)b * Nd + n0 + qh*32 + qs*16 + hi*4 + r) * 64 + ds*16 + lo] = f2bf(o);
                }
            }
        }
    }
}

// ---------------- K3: output projection + residual ----------------
__global__ __launch_bounds__(256) void k_oproj(
    const unsigned short* __restrict__ o_nd,
    const unsigned short* __restrict__ wo,
    const float* __restrict__ bo,
    const float* __restrict__ gamma,
    const float* __restrict__ x,
    float* __restrict__ out)
{
    const int b   = blockIdx.y;
    const int n0  = blockIdx.x * 64;
    const int tid = threadIdx.x, wid = tid >> 6, l = tid & 63;
    const int lo  = l & 15, hi = l >> 4;
    const int n0w = n0 + wid * 16;
    const float g = gamma[0];

    bf16x8 ao[2];
    #pragma unroll
    for (int kc = 0; kc < 2; ++kc)
        ao[kc] = ld_bf8(o_nd + ((size_t)b * Nd + n0w + lo) * 64 + kc*32 + hi*8);

    for (int ct = 0; ct < 32; ++ct) {
        f32x4 acc = {};
        #pragma unroll
        for (int kc = 0; kc < 2; ++kc) {
            bf16x8 bw = ld_bf8(wo + (ct*16 + lo) * 64 + kc*32 + hi*8);
            acc = mfma16(ao[kc], bw, acc);
        }
        const int c = ct*16 + lo;
        const float bc = bo[c];
        const size_t base = ((size_t)b * Cd + c) * Nd + n0w + hi*4;
        float4_t xv = *(const float4_t*)(x + base);
        float4_t ov;
        #pragma unroll
        for (int r = 0; r < 4; ++r) ov[r] = g * (acc[r] + bc) + xv[r];
        *(float4_t*)(out + base) = ov;
    }
}

extern "C" void kernel_launch(void* const* d_in, const int* in_sizes, int n_in,
                              void* d_out, int out_size, void* d_ws, size_t ws_size,
                              hipStream_t stream) {
    (void)in_sizes; (void)n_in; (void)out_size; (void)ws_size;
    const float* x  = (const float*)d_in[0];
    const float* Wq = (const float*)d_in[1];
    const float* bq = (const float*)d_in[2];
    const float* Wk = (const float*)d_in[3];
    const float* bk = (const float*)d_in[4];
    const float* Wv = (const float*)d_in[5];
    const float* bv = (const float*)d_in[6];
    const float* Wo = (const float*)d_in[7];
    const float* bo = (const float*)d_in[8];
    const float* gm = (const float*)d_in[9];
    float* out = (float*)d_out;

    unsigned short* w4   = (unsigned short*)d_ws;          // 4 x 32768 bf16 weights
    unsigned short* q_nd = w4 + 131072;
    unsigned short* k_nd = q_nd + (size_t)Bd * Nd * Dd;
    unsigned short* v_dn = k_nd + (size_t)Bd * Nd * Dd;
    unsigned short* o_nd = v_dn + (size_t)Bd * Nd * Dd;

    k_cvtw<<<128, 256, 0, stream>>>(Wq, Wk, Wv, Wo, w4);
    dim3 gq(Nd / 64, Bd);
    k_qkv<<<gq, 256, 0, stream>>>(x, w4, w4 + 32768, w4 + 65536, bq, bk, bv, q_nd, k_nd, v_dn);
    k_attn<<<512, 256, 0, stream>>>(q_nd, k_nd, v_dn, o_nd);
    dim3 g1(Nd / 64, Bd);
    k_oproj<<<g1, 256, 0, stream>>>(o_nd, w4 + 98304, bo, gm, x, out);
}

// Round 9
// 144.130 us; speedup vs baseline: 1.5857x; 1.0563x over previous
//
#include <hip/hip_runtime.h>
#include <hip/hip_bf16.h>

#define DEVFN __device__ __forceinline__

typedef __bf16 bf16x8 __attribute__((ext_vector_type(8)));
typedef float f32x4 __attribute__((ext_vector_type(4)));
typedef float float4_t __attribute__((ext_vector_type(4)));
typedef unsigned short ushort8_t __attribute__((ext_vector_type(8)));
typedef unsigned short ushort4_t __attribute__((ext_vector_type(4)));
typedef unsigned int uint4_t __attribute__((ext_vector_type(4)));

constexpr int Bd = 8, Cd = 512, Nd = 4096, Dd = 64;

DEVFN unsigned short f2bf(float f) {
    union { float f; unsigned int u; } v; v.f = f;
    unsigned int r = (v.u + 0x7FFFu + ((v.u >> 16) & 1u)) >> 16;
    return (unsigned short)r;
}

DEVFN unsigned int pack2(float a, float b) {   // two f32 -> packed bf16x2 (RNE)
    __hip_bfloat162 h = __float22bfloat162_rn(make_float2(a, b));
    union { __hip_bfloat162 h; unsigned int u; } c; c.h = h;
    return c.u;
}

DEVFN bf16x8 ld_bf8(const unsigned short* p) {
    ushort8_t u = *(const ushort8_t*)p;
    return __builtin_bit_cast(bf16x8, u);
}

DEVFN f32x4 mfma16(bf16x8 a, bf16x8 b, f32x4 c) {
    return __builtin_amdgcn_mfma_f32_16x16x32_bf16(a, b, c, 0, 0, 0);
}

// ---------------- K0: convert weights to bf16 ----------------
__global__ __launch_bounds__(256) void k_cvtw(
    const float* __restrict__ Wq, const float* __restrict__ Wk,
    const float* __restrict__ Wv, const float* __restrict__ Wo,
    unsigned short* __restrict__ w4)
{
    int i = blockIdx.x * 256 + threadIdx.x;   // 0..32767
    w4[i]          = f2bf(Wq[i]);
    w4[32768 + i]  = f2bf(Wk[i]);
    w4[65536 + i]  = f2bf(Wv[i]);
    w4[98304 + i]  = f2bf(Wo[i]);
}

// ---------------- K1 v4: QKV, 2-deep pipelined, 128-thr/32n blocks ----------------
// out(N,D) = x^T W^T per batch. Grid 128x8 = 1024 blocks (4/CU), 2 waves each
// owning 16 n-rows x all 12 d-tiles. x chunk [64c][32n] f32 staged (coalesced
// float4) into LDS transposed bf16 [32n][64c+8]; A-frag = one ds_read_b128;
// B-frags = contiguous 16B weight loads (L2-hot).
// 2-deep: gload(t+2) at top, dswrite(t+1) at bottom -> staged regs have two
// full compute phases of latency cover (round-8 lesson: 1-deep exposes HBM RT).
__global__ __launch_bounds__(128, 2) void k_qkv(
    const float* __restrict__ x,
    const unsigned short* __restrict__ wq,
    const unsigned short* __restrict__ wk,
    const unsigned short* __restrict__ wv,
    const float* __restrict__ bq, const float* __restrict__ bk, const float* __restrict__ bv,
    unsigned short* __restrict__ q_nd, unsigned short* __restrict__ k_nd,
    unsigned short* __restrict__ v_dn)
{
    const int b   = blockIdx.y;
    const int n0  = blockIdx.x * 32;
    const int tid = threadIdx.x, wid = tid >> 6, l = tid & 63;
    const int lo  = l & 15, hi = l >> 4;
    const float* xb = x + (size_t)b * Cd * Nd;

    __shared__ unsigned short smem[2][32][72];   // xt double-buffer; reused by epilogue

    f32x4 acc[12] = {};

    // staging: thread -> c-row (p*16+scr), n-chunk snf*4 (float4); 128B segments
    const int scr = tid >> 3;      // 0..15
    const int snf = tid & 7;       // 0..7
    float4_t xrA[4], xrB[4];

    auto gloadA = [&](int t) {
        const int c0 = t * 64;
        #pragma unroll
        for (int p = 0; p < 4; ++p)
            xrA[p] = *(const float4_t*)(xb + (size_t)(c0 + p*16 + scr) * Nd + n0 + snf*4);
    };
    auto gloadB = [&](int t) {
        const int c0 = t * 64;
        #pragma unroll
        for (int p = 0; p < 4; ++p)
            xrB[p] = *(const float4_t*)(xb + (size_t)(c0 + p*16 + scr) * Nd + n0 + snf*4);
    };
    auto dswriteA = [&](int buf) {
        #pragma unroll
        for (int p = 0; p < 4; ++p)
            #pragma unroll
            for (int i = 0; i < 4; ++i)
                smem[buf][snf*4 + i][p*16 + scr] = f2bf(xrA[p][i]);
    };
    auto dswriteB = [&](int buf) {
        #pragma unroll
        for (int p = 0; p < 4; ++p)
            #pragma unroll
            for (int i = 0; i < 4; ++i)
                smem[buf][snf*4 + i][p*16 + scr] = f2bf(xrB[p][i]);
    };
    auto compute = [&](int buf, int t) {
        const int c0 = t * 64;
        #pragma unroll
        for (int kk = 0; kk < 2; ++kk) {
            bf16x8 af = ld_bf8(&smem[buf][wid*16 + lo][kk*32 + hi*8]);
            #pragma unroll
            for (int j = 0; j < 12; ++j) {
                const unsigned short* wm = (j < 4) ? wq : (j < 8) ? wk : wv;
                const int d0 = (j & 3) * 16;
                bf16x8 bf = ld_bf8(wm + (d0 + lo) * Cd + c0 + kk*32 + hi*8);
                acc[j] = mfma16(af, bf, acc[j]);
            }
        }
    };

    // prologue: tile0 -> buf0 (regs A), tile1 loaded (regs B)
    gloadA(0);
    dswriteA(0);
    gloadB(1);
    __syncthreads();
    // tile T lives in buf T&1
    for (int t = 0; t < 8; t += 2) {
        if (t + 2 < 8) gloadA(t + 2);            // prefetch 2 ahead
        __builtin_amdgcn_sched_barrier(0);       // pin loads (round-2 sinking lesson)
        compute(0, t);
        dswriteB(1);                             // tile t+1 (loaded a full iter ago)
        __syncthreads();
        if (t + 3 < 8) gloadB(t + 3);
        __builtin_amdgcn_sched_barrier(0);
        compute(1, t + 1);
        if (t + 2 < 8) dswriteA(0);              // tile t+2 (two compute phases of cover)
        __syncthreads();
    }

    // ---- epilogue: q/k via per-wave transpose (smem[1], wave-private 16 rows) ----
    unsigned short* tl = &smem[1][wid*16][0];    // [16 n-local][72]
    #pragma unroll
    for (int m = 0; m < 2; ++m) {
        const float* bias = m ? bk : bq;
        #pragma unroll
        for (int jj = 0; jj < 4; ++jj) {
            const float bia = bias[jj*16 + lo];
            #pragma unroll
            for (int r = 0; r < 4; ++r)
                tl[(hi*4 + r) * 72 + jj*16 + lo] = f2bf(acc[m*4 + jj][r] + bia);
        }
        asm volatile("" ::: "memory");           // in-wave: reads after writes
        const int row = l >> 2, dg = l & 3;
        ushort8_t a0 = *(const ushort8_t*)&tl[row*72 + dg*16];
        ushort8_t a1 = *(const ushort8_t*)&tl[row*72 + dg*16 + 8];
        unsigned short* dst = (m ? k_nd : q_nd)
            + ((size_t)b * Nd + n0 + wid*16 + row) * 64 + dg*16;
        *(ushort8_t*)dst = a0; *(ushort8_t*)(dst + 8) = a1;
        asm volatile("" ::: "memory");           // m=0 reads before m=1 overwrites
    }

    // ---- epilogue: v via block-wide transpose (smem[0] viewed as [64][36]) ----
    unsigned short* vt = &smem[0][0][0];
    #pragma unroll
    for (int jj = 0; jj < 4; ++jj) {
        const float bia = bv[jj*16 + lo];
        #pragma unroll
        for (int r = 0; r < 4; ++r)
            vt[(jj*16 + lo) * 36 + wid*16 + hi*4 + r] = f2bf(acc[8 + jj][r] + bia);
    }
    __syncthreads();
    #pragma unroll
    for (int p = 0; p < 2; ++p) {
        const int d = p*32 + (tid >> 2), ng = tid & 3;
        ushort4_t a0 = *(const ushort4_t*)&vt[d*36 + ng*8];
        ushort4_t a1 = *(const ushort4_t*)&vt[d*36 + ng*8 + 4];
        unsigned short* dst = v_dn + ((size_t)b * Dd + d) * Nd + n0 + ng*8;
        *(ushort4_t*)dst = a0; *(ushort4_t*)(dst + 4) = a1;
    }
}

// ---------------- K2: flash attention, 2qh x 2kh wave split, lane-local P ----------------
// (unchanged from round 6 — validated)
__global__ __launch_bounds__(256, 2) void k_attn(
    const unsigned short* __restrict__ q_nd,
    const unsigned short* __restrict__ k_nd,
    const unsigned short* __restrict__ v_dn,
    unsigned short* __restrict__ o_nd)
{
    const int bid = blockIdx.x;
    const int b   = bid & 7;            // round-robin XCD dispatch -> batch-per-XCD L2 locality
    const int n0  = (bid >> 3) * 64;
    const int tid = threadIdx.x, wid = tid >> 6, l = tid & 63;
    const int lo  = l & 15, hi = l >> 4;
    const int lsw = lo & 7;
    const int qh  = wid >> 1;           // q-half (32 rows)
    const int kh  = wid & 1;            // key-half (32 keys)
    const int wk0 = kh * 32;

    __shared__ unsigned short k_tiles[2][64 * 64];
    __shared__ unsigned short v_tiles[2][64 * 64];
    __shared__ float red_acc[2][2][4][256];   // [qh][qs][ds][lane*4]
    __shared__ float red_l[2][2][16];         // [qh][qs][lo]

    const unsigned short* qb = q_nd + (size_t)b * Nd * Dd;
    const unsigned short* kb = k_nd + (size_t)b * Nd * Dd;
    const unsigned short* vb = v_dn + (size_t)b * Dd * Nd;

    bf16x8 aq[2][2];
    #pragma unroll
    for (int qs = 0; qs < 2; ++qs)
        #pragma unroll
        for (int kc = 0; kc < 2; ++kc)
            aq[qs][kc] = ld_bf8(qb + (size_t)(n0 + qh*32 + qs*16 + lo) * 64 + kc*32 + hi*8);

    f32x4 acc[2][4] = {};
    float l_p[2] = {0.f, 0.f};

    const int sr = tid >> 3, ss = tid & 7;
    const int kwsl = (ss ^ (sr & 7)) * 8;
    const int vkh = ss >> 2, vsl = ss & 3, vms = vsl >> 1;
    const int vg0 = vkh * 4 + ((2 * vsl) & 3);
    const int vg1 = vkh * 4 + ((2 * vsl + 1) & 3);
    const int vsw = sr & 7;
    ushort8_t kr0, kr1, vr0, vr1;

    auto gload = [&](int t) {
        const size_t m1 = (size_t)t * 64;
        kr0 = *(const ushort8_t*)(kb + (m1 + sr) * 64 + ss * 8);
        kr1 = *(const ushort8_t*)(kb + (m1 + 32 + sr) * 64 + ss * 8);
        vr0 = *(const ushort8_t*)(vb + (size_t)sr * Nd + m1 + ss * 8);
        vr1 = *(const ushort8_t*)(vb + (size_t)(32 + sr) * Nd + m1 + ss * 8);
    };
    auto dswrite = [&](int buf) {
        unsigned short* kt = k_tiles[buf];
        unsigned short* vt = v_tiles[buf];
        *(ushort8_t*)(kt + sr * 64 + kwsl)        = kr0;
        *(ushort8_t*)(kt + (32 + sr) * 64 + kwsl) = kr1;
        ushort4_t a0 = __builtin_shufflevector(vr0, vr0, 0, 1, 2, 3);
        ushort4_t a1 = __builtin_shufflevector(vr0, vr0, 4, 5, 6, 7);
        ushort4_t b0 = __builtin_shufflevector(vr1, vr1, 0, 1, 2, 3);
        ushort4_t b1 = __builtin_shufflevector(vr1, vr1, 4, 5, 6, 7);
        *(ushort4_t*)(vt + sr * 64 + (vg0 ^ vsw) * 8 + vms * 4)        = a0;
        *(ushort4_t*)(vt + sr * 64 + (vg1 ^ vsw) * 8 + vms * 4)        = a1;
        *(ushort4_t*)(vt + (32 + sr) * 64 + (vg0 ^ vsw) * 8 + vms * 4) = b0;
        *(ushort4_t*)(vt + (32 + sr) * 64 + (vg1 ^ vsw) * 8 + vms * 4) = b1;
    };

    auto compute = [&](int buf) {
        const unsigned short* kt = k_tiles[buf];
        const unsigned short* vt = v_tiles[buf];
        f32x4 s[2][2] = {};
        #pragma unroll
        for (int ms = 0; ms < 2; ++ms) {
            #pragma unroll
            for (int kc = 0; kc < 2; ++kc) {
                bf16x8 kf = ld_bf8(kt + (wk0 + ms*16 + lo) * 64 + (((kc*4 + hi) ^ lsw) * 8));
                #pragma unroll
                for (int qs = 0; qs < 2; ++qs)
                    s[qs][ms] = mfma16(kf, aq[qs][kc], s[qs][ms]);
            }
        }
        bf16x8 vf[4];
        #pragma unroll
        for (int ds = 0; ds < 4; ++ds)
            vf[ds] = ld_bf8(vt + (ds*16 + lo) * 64 + (((kh*4 + hi) ^ lsw) * 8));
        #pragma unroll
        for (int qs = 0; qs < 2; ++qs) {
            float p[2][4];
            #pragma unroll
            for (int ms = 0; ms < 2; ++ms)
                #pragma unroll
                for (int r = 0; r < 4; ++r)
                    p[ms][r] = __expf(s[qs][ms][r]);
            l_p[qs] += ((p[0][0] + p[0][1]) + (p[0][2] + p[0][3]))
                     + ((p[1][0] + p[1][1]) + (p[1][2] + p[1][3]));
            uint4_t w;
            w[0] = pack2(p[0][0], p[0][1]);
            w[1] = pack2(p[0][2], p[0][3]);
            w[2] = pack2(p[1][0], p[1][1]);
            w[3] = pack2(p[1][2], p[1][3]);
            bf16x8 apf = __builtin_bit_cast(bf16x8, w);
            #pragma unroll
            for (int ds = 0; ds < 4; ++ds)
                acc[qs][ds] = mfma16(apf, vf[ds], acc[qs][ds]);
        }
    };

    constexpr int NT = Nd / 64;
    gload(0);
    dswrite(0);
    __syncthreads();
    for (int t = 0; t < NT; ++t) {
        const int cur = t & 1;
        if (t + 1 < NT) gload(t + 1);
        __builtin_amdgcn_sched_barrier(0);
        compute(cur);
        if (t + 1 < NT) dswrite(cur ^ 1);
        __syncthreads();
    }

    float lh[2];
    #pragma unroll
    for (int qs = 0; qs < 2; ++qs) {
        float ps = l_p[qs];
        ps += __shfl_xor(ps, 16, 64);
        ps += __shfl_xor(ps, 32, 64);
        lh[qs] = ps;
    }
    if (kh == 1) {
        #pragma unroll
        for (int qs = 0; qs < 2; ++qs) {
            #pragma unroll
            for (int ds = 0; ds < 4; ++ds)
                *(f32x4*)&red_acc[qh][qs][ds][l * 4] = acc[qs][ds];
            red_l[qh][qs][lo] = lh[qs];
        }
    }
    __syncthreads();
    if (kh == 0) {
        #pragma unroll
        for (int qs = 0; qs < 2; ++qs) {
            #pragma unroll
            for (int ds = 0; ds < 4; ++ds)
                acc[qs][ds] += *(const f32x4*)&red_acc[qh][qs][ds][l * 4];
            float l_tot = lh[qs] + red_l[qh][qs][lo];
            #pragma unroll
            for (int r = 0; r < 4; ++r) {
                float lq = __shfl(l_tot, hi * 4 + r, 16);
                float rl = 1.0f / lq;
                #pragma unroll
                for (int ds = 0; ds < 4; ++ds) {
                    float o = acc[qs][ds][r] * rl;
                    o_nd[((size_t)b * Nd + n0 + qh*32 + qs*16 + hi*4 + r) * 64 + ds*16 + lo] = f2bf(o);
                }
            }
        }
    }
}

// ---------------- K3: output projection + residual ----------------
__global__ __launch_bounds__(256) void k_oproj(
    const unsigned short* __restrict__ o_nd,
    const unsigned short* __restrict__ wo,
    const float* __restrict__ bo,
    const float* __restrict__ gamma,
    const float* __restrict__ x,
    float* __restrict__ out)
{
    const int b   = blockIdx.y;
    const int n0  = blockIdx.x * 64;
    const int tid = threadIdx.x, wid = tid >> 6, l = tid & 63;
    const int lo  = l & 15, hi = l >> 4;
    const int n0w = n0 + wid * 16;
    const float g = gamma[0];

    bf16x8 ao[2];
    #pragma unroll
    for (int kc = 0; kc < 2; ++kc)
        ao[kc] = ld_bf8(o_nd + ((size_t)b * Nd + n0w + lo) * 64 + kc*32 + hi*8);

    for (int ct = 0; ct < 32; ++ct) {
        f32x4 acc = {};
        #pragma unroll
        for (int kc = 0; kc < 2; ++kc) {
            bf16x8 bw = ld_bf8(wo + (ct*16 + lo) * 64 + kc*32 + hi*8);
            acc = mfma16(ao[kc], bw, acc);
        }
        const int c = ct*16 + lo;
        const float bc = bo[c];
        const size_t base = ((size_t)b * Cd + c) * Nd + n0w + hi*4;
        float4_t xv = *(const float4_t*)(x + base);
        float4_t ov;
        #pragma unroll
        for (int r = 0; r < 4; ++r) ov[r] = g * (acc[r] + bc) + xv[r];
        *(float4_t*)(out + base) = ov;
    }
}

extern "C" void kernel_launch(void* const* d_in, const int* in_sizes, int n_in,
                              void* d_out, int out_size, void* d_ws, size_t ws_size,
                              hipStream_t stream) {
    (void)in_sizes; (void)n_in; (void)out_size; (void)ws_size;
    const float* x  = (const float*)d_in[0];
    const float* Wq = (const float*)d_in[1];
    const float* bq = (const float*)d_in[2];
    const float* Wk = (const float*)d_in[3];
    const float* bk = (const float*)d_in[4];
    const float* Wv = (const float*)d_in[5];
    const float* bv = (const float*)d_in[6];
    const float* Wo = (const float*)d_in[7];
    const float* bo = (const float*)d_in[8];
    const float* gm = (const float*)d_in[9];
    float* out = (float*)d_out;

    unsigned short* w4   = (unsigned short*)d_ws;          // 4 x 32768 bf16 weights
    unsigned short* q_nd = w4 + 131072;
    unsigned short* k_nd = q_nd + (size_t)Bd * Nd * Dd;
    unsigned short* v_dn = k_nd + (size_t)Bd * Nd * Dd;
    unsigned short* o_nd = v_dn + (size_t)Bd * Nd * Dd;

    k_cvtw<<<128, 256, 0, stream>>>(Wq, Wk, Wv, Wo, w4);
    dim3 gq(Nd / 32, Bd);
    k_qkv<<<gq, 128, 0, stream>>>(x, w4, w4 + 32768, w4 + 65536, bq, bk, bv, q_nd, k_nd, v_dn);
    k_attn<<<512, 256, 0, stream>>>(q_nd, k_nd, v_dn, o_nd);
    dim3 g1(Nd / 64, Bd);
    k_oproj<<<g1, 256, 0, stream>>>(o_nd, w4 + 98304, bo, gm, x, out);
}